// Round 17
// baseline (45.425 us; speedup 1.0000x reference)
//
#include <hip/hip_runtime.h>
#include <math.h>

typedef __attribute__((ext_vector_type(8))) short short8;
typedef __attribute__((ext_vector_type(4))) float f32x4;

#define BB 8192      // batch
#define CC 1000      // classes
#define NN 9192      // B + C real columns
#define NPAD 9216    // padded
#define DD 128       // feature dim
#define RBW 32       // rows per WAVE (block covers 4*32 = 128 rows)
#define NSPLIT 8     // column splits -> grid 64x8 = 512 = 2 blocks/CU exactly
#define CPB 1152     // columns per block = 9216/NSPLIT (shared by all 4 waves)
#define NT 36        // 32-col chunks per block
#define K2F 14.426950408889634f   // (1/T) * log2(e)

// ---- workspace layout (float offsets) ----
#define WS_CLS   0        // [1024] int batch histogram
#define WS_META  1024     // [9216*4] float4 per col: (bitcast tcol, rcp0, rcp1, 0)
#define WS_SPART 37888    // [8192*8]  S partials, row-major [row][split]
#define WS_PPART 103424   // [8192*8]  P partials, row-major [row][split]
#define WS_F2    168960   // fragment-major bf16 [9216*128]
#define WS_BS    463872   // [32] final1 block partials

static __device__ __forceinline__ unsigned short f2bf(float x) {
    unsigned int b = __float_as_uint(x);
    unsigned int r = (b + 0x7FFFu + ((b >> 16) & 1u)) >> 16;   // RNE
    return (unsigned short)r;
}
static __device__ __forceinline__ float fexp2(float x) {
    float r; asm("v_exp_f32 %0, %1" : "=v"(r) : "v"(x)); return r;
}
static __device__ __forceinline__ float flog2(float x) {
    float r; asm("v_log_f32 %0, %1" : "=v"(r) : "v"(x)); return r;
}

// ---- fused prep: blocks 0..143 convert fp32 -> fragment-major bf16;
//      block 144: histogram + packed per-column meta table ----
__global__ __launch_bounds__(1024) void prep_kernel(
    const float* __restrict__ feats, const float* __restrict__ ctrs,
    const int* __restrict__ tgt, unsigned short* __restrict__ F2,
    int* __restrict__ cls, float4* __restrict__ meta)
{
    const int tid = threadIdx.x;
    if (blockIdx.x < 144) {
        // cvt: one short8-unit per thread.  F2 fragment-major: 16B unit
        // u = (j16*4 + ks)*64 + l4*16 + l15 holds (col j=j16*16+l15, k=ks*32+l4*8..+8)
        int u = blockIdx.x * 1024 + tid;          // < 147456 = NPAD*16
        int j = u >> 4, quad = u & 15;
        int k0 = quad * 8;
        float4 v0 = {0.f,0.f,0.f,0.f}, v1 = {0.f,0.f,0.f,0.f};
        if (j < BB) {
            v0 = *(const float4*)&feats[(size_t)j * DD + k0];
            v1 = *(const float4*)&feats[(size_t)j * DD + k0 + 4];
        } else if (j < NN) {
            v0 = *(const float4*)&ctrs[(size_t)(j - BB) * DD + k0];
            v1 = *(const float4*)&ctrs[(size_t)(j - BB) * DD + k0 + 4];
        }
        short8 o;
        o[0]=f2bf(v0.x); o[1]=f2bf(v0.y); o[2]=f2bf(v0.z); o[3]=f2bf(v0.w);
        o[4]=f2bf(v1.x); o[5]=f2bf(v1.y); o[6]=f2bf(v1.z); o[7]=f2bf(v1.w);
        size_t offb = (size_t)((((j >> 4) * 4 + (quad >> 2)) * 64 + (quad & 3) * 16 + (j & 15)) * 8);
        *(short8*)&F2[offb] = o;
        return;
    }

    __shared__ int h[1024];
    h[tid] = 0;
    __syncthreads();
    for (int i = tid; i < BB; i += 1024) atomicAdd(&h[tgt[i]], 1);
    __syncthreads();

    cls[tid] = h[tid];                    // npos for rows of class tid

    for (int j = tid; j < NPAD; j += 1024) {
        float4 m = {__int_as_float(-2), 0.f, 0.f, 0.f};
        if (j < NN) {
            int c = (j < BB) ? tgt[j] : (j - BB);
            int n = h[c] + 1;             // +1: the class center itself
            m.x = __int_as_float(c);
            m.y = 1.0f / (float)n;
            m.z = (n > 1) ? 1.0f / (float)(n - 1) : 0.0f;
        }
        meta[j] = m;
    }
}

// one 32-col x 128-k chunk: 8 x 1KB coalesced loads
static __device__ __forceinline__ void loadB32(const unsigned short* __restrict__ F2,
                                               int j0, int lane8, short8 (&buf)[8]) {
#pragma unroll
    for (int fn = 0; fn < 2; ++fn)
#pragma unroll
        for (int ks = 0; ks < 4; ++ks)
            buf[fn * 4 + ks] = *(const short8*)&F2[(size_t)(((((j0 >> 4) + fn) * 4 + ks) * 512) + lane8)];
}

// 16 MFMAs: 32 rows x 32 cols x full K=128
static __device__ __forceinline__ void mfma32(const short8 (&af)[4][2], const short8 (&b)[8],
                                              f32x4 (&acc)[2][2]) {
    const f32x4 z4 = {0.f, 0.f, 0.f, 0.f};
#pragma unroll
    for (int fm = 0; fm < 2; ++fm)
#pragma unroll
        for (int fn = 0; fn < 2; ++fn)
            acc[fm][fn] = __builtin_amdgcn_mfma_f32_16x16x32_bf16(af[0][fm], b[fn * 4], z4, 0, 0, 0);
#pragma unroll
    for (int ks = 1; ks < 4; ++ks)
#pragma unroll
        for (int fm = 0; fm < 2; ++fm)
#pragma unroll
            for (int fn = 0; fn < 2; ++fn)
                acc[fm][fn] = __builtin_amdgcn_mfma_f32_16x16x32_bf16(
                    af[ks][fm], b[fn * 4 + ks], acc[fm][fn], 0, 0, 0);
}

// fused mask epilogue: ~6 VALU + 1 trans per element
template<bool DIAG>
static __device__ __forceinline__ void epi32(const f32x4 (&acc)[2][2], const float4 (&mt)[2],
                                             int j0, int l15, int rowbase,
                                             const int (&ti)[8],
                                             float (&Sl)[8], float (&Pl)[8]) {
#pragma unroll
    for (int fn = 0; fn < 2; ++fn) {
        const int tj = __float_as_int(mt[fn].x);
        const float r0 = mt[fn].y, r1 = mt[fn].z;
        const int col = j0 + fn * 16 + l15;
#pragma unroll
        for (int fm = 0; fm < 2; ++fm)
#pragma unroll
            for (int q = 0; q < 4; ++q) {
                const int x = fm * 4 + q;
                float d = acc[fm][fn][q];
                float l2 = fmaf(d, K2F, -K2F);
                float e = fexp2(l2);
                bool m = (tj == ti[x]);
                if (DIAG) {
                    bool self = (col == rowbase + fm * 16 + q);
                    if (self) { e = 0.f; m = false; }
                }
                float rw = m ? r1 : r0;
                Sl[x] = fmaf(e, rw, Sl[x]);       // padded cols: rcp=0
                Pl[x] += m ? d : 0.f;             // sum of masked raw dots
            }
    }
}

__global__ __launch_bounds__(256, 2) void main_kernel(
    const unsigned short* __restrict__ F2, const float4* __restrict__ meta,
    float* __restrict__ S_part, float* __restrict__ P_part)
{
    const int tid  = threadIdx.x;
    const int lane = tid & 63;
    const int wave = tid >> 6;
    const int l15 = lane & 15, l4 = lane >> 4;
    const int lane8 = lane * 8;
    const int row0 = blockIdx.x * (4 * RBW) + wave * RBW;  // per-wave 32-row group
    const int split = blockIdx.y;
    const int cb = split * CPB;                  // SAME columns for all 4 waves -> L1 reuse
    const int rowbase = row0 + l4 * 4;

    // A fragments straight from global (this wave's 32 rows), persistent
    short8 af[4][2];                             // [ks][fm]
#pragma unroll
    for (int fm = 0; fm < 2; ++fm)
#pragma unroll
        for (int ks = 0; ks < 4; ++ks)
            af[ks][fm] = *(const short8*)&F2[(size_t)((((row0 >> 4) + fm) * 4 + ks) * 512 + lane8)];

    int ti[8];                                   // row classes for this lane's 8 rows
#pragma unroll
    for (int fm = 0; fm < 2; ++fm)
#pragma unroll
        for (int q = 0; q < 4; ++q)
            ti[fm * 4 + q] = __float_as_int(meta[rowbase + fm * 16 + q].x);

    float Sl[8], Pl[8];
#pragma unroll
    for (int x = 0; x < 8; ++x) { Sl[x] = 0.f; Pl[x] = 0.f; }

    // 2 named buffers, issue-next-before-compute-current (rule #20: static indexing)
    short8 bA[8], bB[8];
    float4 mA[2], mB[2];
    loadB32(F2, cb, lane8, bA);
    mA[0] = meta[cb + l15]; mA[1] = meta[cb + 16 + l15];

#pragma unroll 1
    for (int tt = 0; tt < NT; tt += 2) {
        {   // compute chunk tt from bA, prefetch tt+1 into bB
            if (tt + 1 < NT) {
                int j = cb + (tt + 1) * 32;
                loadB32(F2, j, lane8, bB);
                mB[0] = meta[j + l15]; mB[1] = meta[j + 16 + l15];
            }
            const int j0 = cb + tt * 32;
            f32x4 acc[2][2];
            mfma32(af, bA, acc);
            if (j0 == row0) epi32<true >(acc, mA, j0, l15, rowbase, ti, Sl, Pl);
            else            epi32<false>(acc, mA, j0, l15, rowbase, ti, Sl, Pl);
        }
        {   // compute chunk tt+1 from bB, prefetch tt+2 into bA
            if (tt + 2 < NT) {
                int j = cb + (tt + 2) * 32;
                loadB32(F2, j, lane8, bA);
                mA[0] = meta[j + l15]; mA[1] = meta[j + 16 + l15];
            }
            const int j0 = cb + (tt + 1) * 32;
            f32x4 acc[2][2];
            mfma32(af, bB, acc);
            if (j0 == row0) epi32<true >(acc, mB, j0, l15, rowbase, ti, Sl, Pl);
            else            epi32<false>(acc, mB, j0, l15, rowbase, ti, Sl, Pl);
        }
    }

    // 16-lane column reduce (tree); waves own disjoint rows -> direct write, no barrier
    // partials stored row-major [row][split] so final1 reads are contiguous per row
#pragma unroll
    for (int idx = 0; idx < 8; ++idx) {
        float S = Sl[idx], P = Pl[idx];
#pragma unroll
        for (int off = 1; off < 16; off <<= 1) {
            S += __shfl_xor(S, off, 64);
            P += __shfl_xor(P, off, 64);
        }
        if (l15 == 0) {
            int row = row0 + (idx >> 2) * 16 + l4 * 4 + (idx & 3);
            S_part[(size_t)row * NSPLIT + split] = S;
            P_part[(size_t)row * NSPLIT + split] = P;
        }
    }
}

// 32 blocks x 256 threads: one row per thread, coalesced [row][split] reads
__global__ __launch_bounds__(256) void final1_kernel(
    const int* __restrict__ tgt, const int* __restrict__ cls,
    const float* __restrict__ S_part, const float* __restrict__ P_part,
    float* __restrict__ bs)
{
    const int tid = threadIdx.x;
    const int i = blockIdx.x * 256 + tid;
    float S = 0.f, P = 0.f;
    const float4* sp = (const float4*)&S_part[(size_t)i * NSPLIT];
    const float4* pp = (const float4*)&P_part[(size_t)i * NSPLIT];
#pragma unroll
    for (int q = 0; q < NSPLIT / 4; ++q) {
        float4 a = sp[q]; S += (a.x + a.y) + (a.z + a.w);
        float4 b = pp[q]; P += (b.x + b.y) + (b.z + b.w);
    }
    const float npos = (float)cls[tgt[i]];
    float lp = fmaf(K2F, P / npos, -K2F) - flog2(S);   // log2 units

#pragma unroll
    for (int off = 1; off < 64; off <<= 1) lp += __shfl_xor(lp, off, 64);
    __shared__ float wsum[4];
    if ((tid & 63) == 0) wsum[tid >> 6] = lp;
    __syncthreads();
    if (tid == 0) bs[blockIdx.x] = wsum[0] + wsum[1] + wsum[2] + wsum[3];
}

__global__ void final2_kernel(const float* __restrict__ bs, float* __restrict__ out) {
    const int t = threadIdx.x;   // 64 threads
    float v = (t < 32) ? bs[t] : 0.f;
#pragma unroll
    for (int off = 1; off < 64; off <<= 1) v += __shfl_xor(v, off, 64);
    if (t == 0) out[0] = -0.6931471805599453f * (v / (float)BB);   // ln2 * mean, negated
}

extern "C" void kernel_launch(void* const* d_in, const int* in_sizes, int n_in,
                              void* d_out, int out_size, void* d_ws, size_t ws_size,
                              hipStream_t stream) {
    const float* ctrs  = (const float*)d_in[0];   // centers1 [1000,128]
    const float* feats = (const float*)d_in[1];   // features [8192,128]
    const int*   tgt   = (const int*)d_in[2];     // targets  [8192] int32
    float* out = (float*)d_out;
    float* ws  = (float*)d_ws;

    int*    cls  = (int*)(ws + WS_CLS);
    float4* meta = (float4*)(ws + WS_META);
    float*  Sp   = ws + WS_SPART;
    float*  Pp   = ws + WS_PPART;
    float*  bs   = ws + WS_BS;
    unsigned short* F2 = (unsigned short*)(ws + WS_F2);

    prep_kernel<<<dim3(145), dim3(1024), 0, stream>>>(feats, ctrs, tgt, F2, cls, meta);
    main_kernel<<<dim3(BB / (4 * RBW), NSPLIT), dim3(256), 0, stream>>>(F2, meta, Sp, Pp);
    final1_kernel<<<dim3(BB / 256), dim3(256), 0, stream>>>(tgt, cls, Sp, Pp, bs);
    final2_kernel<<<dim3(1), dim3(64), 0, stream>>>(bs, out);
}